// Round 2
// baseline (4622.260 us; speedup 1.0000x reference)
//
#include <hip/hip_runtime.h>
#include <hip/hip_bf16.h>

typedef short short8 __attribute__((ext_vector_type(8)));
typedef float f32x4 __attribute__((ext_vector_type(4)));

// ---- workspace layout (bytes) ----
#define OFF_U   0x0UL        // U bf16 [1024][1024]        2 MiB
#define OFF_W   0x200000UL   // W bf16 [1024][512]         1 MiB
#define OFF_PRE 0x300000UL   // pre bf16 [t=512][b=128][i=1024]  128 MiB
#define OFF_H0  0x8300000UL  // h buf0 bf16 [128][1024]    256 KiB
#define OFF_H1  0x8340000UL  // h buf1 bf16 [128][1024]    256 KiB
#define OFF_CNT 0x8380000UL  // flags uint [8 clusters][64 waves]  2 KiB

static __device__ __forceinline__ unsigned short f2bf(float f) {
  return __builtin_bit_cast(unsigned short, __float2bfloat16(f));
}
static __device__ __forceinline__ float bf2f(unsigned short u) {
  unsigned int v = (unsigned int)u << 16;
  return __builtin_bit_cast(float, v);
}
static __device__ __forceinline__ unsigned int pack2(float a, float b) {
  return (unsigned int)f2bf(a) | ((unsigned int)f2bf(b) << 16);
}
static __device__ __forceinline__ float fast_tanh(float x) {
  float xc = fminf(fmaxf(x, -10.f), 10.f);
  float e2 = __expf(2.f * xc);
  return 1.f - 2.f * __builtin_amdgcn_rcpf(e2 + 1.f);
}

// ---------------- fp32 -> bf16 bulk convert ----------------
__global__ __launch_bounds__(256) void cvt_bf16(const float* __restrict__ in,
                                                unsigned short* __restrict__ out, int n4) {
  int idx = blockIdx.x * 256 + threadIdx.x;
  if (idx < n4) {
    float4 v = *(const float4*)&in[idx * 4];
    uint2 p; p.x = pack2(v.x, v.y); p.y = pack2(v.z, v.w);
    *(uint2*)&out[idx * 4] = p;
  }
}

// ---------------- pre = gather(emb,x) @ W^T   (stored [t][b][i], bf16, NO bias) --------
__global__ __launch_bounds__(256) void pre_gemm(const int* __restrict__ x,
                                                const float* __restrict__ emb,
                                                const unsigned short* __restrict__ Wbf,
                                                unsigned short* __restrict__ pre) {
  const int t   = blockIdx.y;           // 0..511
  const int n0  = blockIdx.x * 128;     // i offset
  const int tid = threadIdx.x;
  const int lane = tid & 63, w = tid >> 6;
  const int q = lane >> 4, l15 = lane & 15;

  __shared__ unsigned short Alds[128][72];  // +8 pad
  __shared__ unsigned short Blds[128][72];
  __shared__ int tok[128];
  if (tid < 128) tok[tid] = x[tid * 512 + t];   // x[b][t]
  __syncthreads();

  f32x4 acc[4][4];
  #pragma unroll
  for (int a = 0; a < 4; ++a)
    #pragma unroll
    for (int b = 0; b < 4; ++b) acc[a][b] = {0.f, 0.f, 0.f, 0.f};

  const int wm = (w & 1) * 64, wn = (w >> 1) * 64;

  for (int k0 = 0; k0 < 512; k0 += 64) {
    #pragma unroll
    for (int it = 0; it < 8; ++it) {
      int idx = it * 256 + tid;
      int r = idx >> 4, c4 = (idx & 15) * 4;
      float4 v = *(const float4*)&emb[tok[r] * 512 + k0 + c4];
      uint2 p; p.x = pack2(v.x, v.y); p.y = pack2(v.z, v.w);
      *(uint2*)&Alds[r][c4] = p;
    }
    #pragma unroll
    for (int it = 0; it < 4; ++it) {
      int idx = it * 256 + tid;
      int r = idx >> 3, c8 = (idx & 7) * 8;
      *(int4*)&Blds[r][c8] = *(const int4*)&Wbf[(n0 + r) * 512 + k0 + c8];
    }
    __syncthreads();
    #pragma unroll
    for (int kt = 0; kt < 2; ++kt) {
      short8 af[4], bfr[4];
      #pragma unroll
      for (int mt = 0; mt < 4; ++mt) af[mt]  = *(const short8*)&Alds[wm + mt*16 + l15][kt*32 + q*8];
      #pragma unroll
      for (int nt = 0; nt < 4; ++nt) bfr[nt] = *(const short8*)&Blds[wn + nt*16 + l15][kt*32 + q*8];
      #pragma unroll
      for (int mt = 0; mt < 4; ++mt)
        #pragma unroll
        for (int nt = 0; nt < 4; ++nt)
          acc[mt][nt] = __builtin_amdgcn_mfma_f32_16x16x32_bf16(af[mt], bfr[nt], acc[mt][nt], 0, 0, 0);
    }
    __syncthreads();
  }
  #pragma unroll
  for (int mt = 0; mt < 4; ++mt) {
    int brow = wm + mt * 16 + q * 4;
    #pragma unroll
    for (int nt = 0; nt < 4; ++nt) {
      int i = n0 + wn + nt * 16 + l15;
      #pragma unroll
      for (int r = 0; r < 4; ++r)
        pre[(t * 128 + brow + r) * 1024 + i] = f2bf(acc[mt][nt][r]);
    }
  }
}

// ---------------- persistent recurrence ----------------
// 64 wgs = 8 clusters (16 batch) x 8 i-slices (128 rows). wg = 8 waves, each wave
// owns 16 i-rows x full K=1024; U slice resident in 128 VGPRs/lane.
// Sync: per-wave monotonic flags through MALL (sc1 bypass, no L2 wb/inv).
__global__ __launch_bounds__(512, 2) void recurrence(const unsigned short* __restrict__ Ubf,
                                                     const unsigned short* __restrict__ pre,
                                                     const float* __restrict__ Wb,
                                                     const float* __restrict__ Ub,
                                                     unsigned short* __restrict__ h0buf,
                                                     unsigned short* __restrict__ h1buf,
                                                     unsigned int* __restrict__ cnt) {
  const int c   = blockIdx.x & 7;        // cluster (XCD-affine under round-robin; perf only)
  const int s   = blockIdx.x >> 3;       // i-slice
  const int tid = threadIdx.x;
  const int lane = tid & 63, wv = tid >> 6;
  const int q = lane >> 4, l15 = lane & 15;
  const int ibase = s * 128 + wv * 16;   // this wave's 16 i-rows
  const int bglob = c * 16;

  __shared__ unsigned short hlds[16][1032];   // [b][k], +8 pad (2-way max = free)

  // U A-fragments: 32 k-tiles, resident all 512 steps (128 VGPRs)
  short8 A[32];
  {
    const unsigned short* Up = Ubf + (ibase + l15) * 1024 + q * 8;
    #pragma unroll
    for (int kt = 0; kt < 32; ++kt) A[kt] = *(const short8*)(Up + kt * 32);
  }
  float4 bias;
  {
    int i0 = ibase + q * 4;
    float4 wb = *(const float4*)&Wb[i0];
    float4 ub = *(const float4*)&Ub[i0];
    bias = make_float4(wb.x + ub.x, wb.y + ub.y, wb.z + ub.z, wb.w + ub.w);
  }

  unsigned int* flags = cnt + c * 64;
  const unsigned int* fpoll = flags + lane;           // lane j polls producer j
  unsigned int* fmine = flags + (s * 8 + wv);

  // staging geometry: each thread loads 4 x int4 (rows sb, sb+4, sb+8, sb+12)
  const int sb = tid >> 7;              // 0..3
  const int sk = (tid & 127) * 8;       // shorts

  const unsigned short* prebase = pre + (size_t)(bglob + l15) * 1024 + ibase + q * 4;
  unsigned short* dstoff = (unsigned short*)((size_t)((bglob + l15) * 1024 + ibase + q * 4) * 2);

  #pragma unroll 1
  for (int t = 0; t < 512; ++t) {
    // prefetch pre (independent of sync; hides latency under poll)
    ushort4 pv = *(const ushort4*)(prebase + (size_t)t * 131072);

    const unsigned short* hprev = (t & 1) ? h1buf : h0buf;
    unsigned short* hnew        = (t & 1) ? h0buf : h1buf;

    if (t > 0) {
      const unsigned int tt = (unsigned int)t;
      for (;;) {
        unsigned int v;
        asm volatile("global_load_dword %0, %1, off sc1\n\ts_waitcnt vmcnt(0)"
                     : "=v"(v) : "v"(fpoll) : "memory");
        if (__ballot(v < tt) == 0) break;   // all 64 producer-waves posted step t-1
      }
    }

    // stage h[16][1024] -> LDS via sc1 (MALL-coherent) loads
    {
      const unsigned short* hp = hprev + (size_t)(bglob + sb) * 1024 + sk;
      int4 r0, r1, r2, r3;
      asm volatile(
        "global_load_dwordx4 %0, %4, off sc1\n\t"
        "global_load_dwordx4 %1, %5, off sc1\n\t"
        "global_load_dwordx4 %2, %6, off sc1\n\t"
        "global_load_dwordx4 %3, %7, off sc1\n\t"
        "s_waitcnt vmcnt(0)"
        : "=&v"(r0), "=&v"(r1), "=&v"(r2), "=&v"(r3)
        : "v"(hp), "v"(hp + 4 * 1024), "v"(hp + 8 * 1024), "v"(hp + 12 * 1024)
        : "memory");
      *(int4*)&hlds[sb][sk]      = r0;
      *(int4*)&hlds[sb + 4][sk]  = r1;
      *(int4*)&hlds[sb + 8][sk]  = r2;
      *(int4*)&hlds[sb + 12][sk] = r3;
    }
    __syncthreads();   // the only barrier per step

    f32x4 acc0 = {0.f, 0.f, 0.f, 0.f}, acc1 = {0.f, 0.f, 0.f, 0.f};
    #pragma unroll
    for (int kt = 0; kt < 32; kt += 2) {
      short8 b0 = *(const short8*)&hlds[l15][kt * 32 + q * 8];
      short8 b1 = *(const short8*)&hlds[l15][kt * 32 + 32 + q * 8];
      acc0 = __builtin_amdgcn_mfma_f32_16x16x32_bf16(A[kt],     b0, acc0, 0, 0, 0);
      acc1 = __builtin_amdgcn_mfma_f32_16x16x32_bf16(A[kt + 1], b1, acc1, 0, 0, 0);
    }

    // epilogue: D col=lane&15 -> batch, row=4q+r -> i
    float x0 = acc0[0] + acc1[0] + bf2f(pv.x) + bias.x;
    float x1 = acc0[1] + acc1[1] + bf2f(pv.y) + bias.y;
    float x2 = acc0[2] + acc1[2] + bf2f(pv.z) + bias.z;
    float x3 = acc0[3] + acc1[3] + bf2f(pv.w) + bias.w;
    uint2 pk;
    pk.x = pack2(fast_tanh(x0), fast_tanh(x1));
    pk.y = pack2(fast_tanh(x2), fast_tanh(x3));

    {
      unsigned short* dst = hnew + (size_t)(bglob + l15) * 1024 + ibase + q * 4;
      (void)dstoff;
      asm volatile("global_store_dwordx2 %0, %1, off sc1\n\t"
                   "s_waitcnt vmcnt(0)"
                   : : "v"(dst), "v"(pk) : "memory");
    }
    if (lane == 0) {
      unsigned int tv = (unsigned int)(t + 1);
      asm volatile("global_store_dword %0, %1, off sc1"
                   : : "v"(fmine), "v"(tv) : "memory");
    }
    // no trailing barrier: next step's poll (needs own wg's flags) is the barrier
  }
}

// ---------------- final: sigmoid(h_T @ V^T + Vb) ----------------
__global__ __launch_bounds__(64) void final_out(const unsigned short* __restrict__ hT,
                                                const float* __restrict__ Vw,
                                                const float* __restrict__ Vb,
                                                float* __restrict__ out) {
  int b = blockIdx.x, lane = threadIdx.x;
  float sum = 0.f;
  #pragma unroll
  for (int k = 0; k < 16; ++k) {
    int i = k * 64 + lane;
    sum += bf2f(hT[b * 1024 + i]) * Vw[i];
  }
  #pragma unroll
  for (int off = 32; off; off >>= 1) sum += __shfl_down(sum, off);
  if (lane == 0) out[b] = 1.f / (1.f + expf(-(sum + Vb[0])));
}

extern "C" void kernel_launch(void* const* d_in, const int* in_sizes, int n_in,
                              void* d_out, int out_size, void* d_ws, size_t ws_size,
                              hipStream_t stream) {
  const int*   x   = (const int*)d_in[0];
  const float* emb = (const float*)d_in[1];
  const float* W_w = (const float*)d_in[2];
  const float* W_b = (const float*)d_in[3];
  const float* U_w = (const float*)d_in[4];
  const float* U_b = (const float*)d_in[5];
  const float* V_w = (const float*)d_in[6];
  const float* V_b = (const float*)d_in[7];
  float* out = (float*)d_out;
  char*  ws  = (char*)d_ws;

  unsigned short* Ubf = (unsigned short*)(ws + OFF_U);
  unsigned short* Wbf = (unsigned short*)(ws + OFF_W);
  unsigned short* pre = (unsigned short*)(ws + OFF_PRE);
  unsigned short* h0  = (unsigned short*)(ws + OFF_H0);
  unsigned short* h1  = (unsigned short*)(ws + OFF_H1);
  unsigned int*   cnt = (unsigned int*)(ws + OFF_CNT);

  // zero h0 (initial hidden state) + h1 + flags
  hipMemsetAsync(ws + OFF_H0, 0, (OFF_CNT - OFF_H0) + 0x1000, stream);

  cvt_bf16<<<1024, 256, 0, stream>>>(U_w, Ubf, 1024 * 1024 / 4);
  cvt_bf16<<<512, 256, 0, stream>>>(W_w, Wbf, 1024 * 512 / 4);

  pre_gemm<<<dim3(8, 512), 256, 0, stream>>>(x, emb, Wbf, pre);

  void* args[] = {&Ubf, &pre, &W_b, &U_b, &h0, &h1, &cnt};
  hipLaunchCooperativeKernel((void*)recurrence, dim3(64), dim3(512), args, 0, stream);

  final_out<<<128, 64, 0, stream>>>(h0, V_w, V_b, out);
}

// Round 4
// 1860.121 us; speedup vs baseline: 2.4849x; 2.4849x over previous
//
#include <hip/hip_runtime.h>
#include <hip/hip_bf16.h>

typedef short short8 __attribute__((ext_vector_type(8)));
typedef float f32x4 __attribute__((ext_vector_type(4)));

// ---- workspace layout (bytes) ----
#define OFF_U   0x0UL        // U bf16 [1024][1024]        2 MiB
#define OFF_W   0x200000UL   // W bf16 [1024][512]         1 MiB
#define OFF_PRE 0x300000UL   // pre bf16 [t=512][b=128][i=1024]  128 MiB
#define OFF_H0  0x8300000UL  // h buf0 bf16 [128][1024]    256 KiB
#define OFF_H1  0x8340000UL  // h buf1 bf16 [128][1024]    256 KiB
#define OFF_CNT 0x8380000UL  // flags uint[8 clusters][64 waves]  2 KiB

static __device__ __forceinline__ unsigned short f2bf(float f) {
  return __builtin_bit_cast(unsigned short, __float2bfloat16(f));
}
static __device__ __forceinline__ float bf2f(unsigned short u) {
  unsigned int v = (unsigned int)u << 16;
  return __builtin_bit_cast(float, v);
}
static __device__ __forceinline__ unsigned int pack2(float a, float b) {
  return (unsigned int)f2bf(a) | ((unsigned int)f2bf(b) << 16);
}
static __device__ __forceinline__ float fast_tanh(float x) {
  float xc = fminf(fmaxf(x, -10.f), 10.f);
  float e2 = __expf(2.f * xc);
  return 1.f - 2.f * __builtin_amdgcn_rcpf(e2 + 1.f);
}

// ---------------- fp32 -> bf16 bulk convert ----------------
__global__ __launch_bounds__(256) void cvt_bf16(const float* __restrict__ in,
                                                unsigned short* __restrict__ out, int n4) {
  int idx = blockIdx.x * 256 + threadIdx.x;
  if (idx < n4) {
    float4 v = *(const float4*)&in[idx * 4];
    uint2 p; p.x = pack2(v.x, v.y); p.y = pack2(v.z, v.w);
    *(uint2*)&out[idx * 4] = p;
  }
}

// ---------------- pre = gather(emb,x) @ W^T   (stored [t][b][i], bf16, NO bias) --------
__global__ __launch_bounds__(256) void pre_gemm(const int* __restrict__ x,
                                                const float* __restrict__ emb,
                                                const unsigned short* __restrict__ Wbf,
                                                unsigned short* __restrict__ pre) {
  const int t   = blockIdx.y;           // 0..511
  const int n0  = blockIdx.x * 128;     // i offset
  const int tid = threadIdx.x;
  const int lane = tid & 63, w = tid >> 6;
  const int q = lane >> 4, l15 = lane & 15;

  __shared__ unsigned short Alds[128][72];  // +8 pad
  __shared__ unsigned short Blds[128][72];
  __shared__ int tok[128];
  if (tid < 128) tok[tid] = x[tid * 512 + t];   // x[b][t]
  __syncthreads();

  f32x4 acc[4][4];
  #pragma unroll
  for (int a = 0; a < 4; ++a)
    #pragma unroll
    for (int b = 0; b < 4; ++b) acc[a][b] = {0.f, 0.f, 0.f, 0.f};

  const int wm = (w & 1) * 64, wn = (w >> 1) * 64;

  for (int k0 = 0; k0 < 512; k0 += 64) {
    #pragma unroll
    for (int it = 0; it < 8; ++it) {
      int idx = it * 256 + tid;
      int r = idx >> 4, c4 = (idx & 15) * 4;
      float4 v = *(const float4*)&emb[tok[r] * 512 + k0 + c4];
      uint2 p; p.x = pack2(v.x, v.y); p.y = pack2(v.z, v.w);
      *(uint2*)&Alds[r][c4] = p;
    }
    #pragma unroll
    for (int it = 0; it < 4; ++it) {
      int idx = it * 256 + tid;
      int r = idx >> 3, c8 = (idx & 7) * 8;
      *(int4*)&Blds[r][c8] = *(const int4*)&Wbf[(n0 + r) * 512 + k0 + c8];
    }
    __syncthreads();
    #pragma unroll
    for (int kt = 0; kt < 2; ++kt) {
      short8 af[4], bfr[4];
      #pragma unroll
      for (int mt = 0; mt < 4; ++mt) af[mt]  = *(const short8*)&Alds[wm + mt*16 + l15][kt*32 + q*8];
      #pragma unroll
      for (int nt = 0; nt < 4; ++nt) bfr[nt] = *(const short8*)&Blds[wn + nt*16 + l15][kt*32 + q*8];
      #pragma unroll
      for (int mt = 0; mt < 4; ++mt)
        #pragma unroll
        for (int nt = 0; nt < 4; ++nt)
          acc[mt][nt] = __builtin_amdgcn_mfma_f32_16x16x32_bf16(af[mt], bfr[nt], acc[mt][nt], 0, 0, 0);
    }
    __syncthreads();
  }
  #pragma unroll
  for (int mt = 0; mt < 4; ++mt) {
    int brow = wm + mt * 16 + q * 4;
    #pragma unroll
    for (int nt = 0; nt < 4; ++nt) {
      int i = n0 + wn + nt * 16 + l15;
      #pragma unroll
      for (int r = 0; r < 4; ++r)
        pre[(t * 128 + brow + r) * 1024 + i] = f2bf(acc[mt][nt][r]);
    }
  }
}

// ---------------- persistent recurrence ----------------
// 64 wgs = 8 clusters (16 batch) x 8 i-slices (128 rows). wg = 8 waves, each wave
// owns 16 i-rows x full K=1024. U slice pinned in 128 VGPRs/lane (laundered via
// opaque asm so in-loop volatile asm cannot force re-loads — VGPR_Count is the test).
// Cross-wg h exchange + flags: sc1 (MALL coherence point; only cross-CU-coherent
// path on gfx950 — sc0 hits stale L1 and deadlocks, round-3 lesson).
// NOTE: in-loop asm carries NO "memory" clobber on purpose: volatile program order
// chains poll -> stage -> barrier -> MFMA -> store -> flag, and U/pre/bias loads
// must stay hoistable/register-resident.
__global__ __launch_bounds__(512, 2) void recurrence(const unsigned short* __restrict__ Ubf,
                                                     const unsigned short* __restrict__ pre,
                                                     const float* __restrict__ Wb,
                                                     const float* __restrict__ Ub,
                                                     unsigned short* __restrict__ h0buf,
                                                     unsigned short* __restrict__ h1buf,
                                                     unsigned int* __restrict__ cnt) {
  const int c   = blockIdx.x & 7;        // cluster
  const int s   = blockIdx.x >> 3;       // i-slice
  const int tid = threadIdx.x;
  const int lane = tid & 63, wv = tid >> 6;
  const int q = lane >> 4, l15 = lane & 15;
  const int ibase = s * 128 + wv * 16;   // this wave's 16 i-rows
  const int bglob = c * 16;

  __shared__ unsigned short hlds[16][1032];   // [b][k], +8 pad (2-way max = free)

  // U A-fragments: 32 k-tiles, pinned resident (128 VGPRs)
  short8 A[32];
  {
    const unsigned short* Up = Ubf + (ibase + l15) * 1024 + q * 8;
    #pragma unroll
    for (int kt = 0; kt < 32; ++kt) A[kt] = *(const short8*)(Up + kt * 32);
  }
  #pragma unroll
  for (int kt = 0; kt < 32; ++kt) asm volatile("" : "+v"(A[kt]));  // opaque: forbid remat

  float4 bias;
  {
    int i0 = ibase + q * 4;
    float4 wb = *(const float4*)&Wb[i0];
    float4 ub = *(const float4*)&Ub[i0];
    bias = make_float4(wb.x + ub.x, wb.y + ub.y, wb.z + ub.z, wb.w + ub.w);
  }

  unsigned int* flags = cnt + c * 64;
  const unsigned int* fpoll = flags + lane;       // lane j polls producer-wave j
  unsigned int* fmine = flags + (s * 8 + wv);
  const int sb = tid >> 7;              // staging row 0..3
  const int sk = (tid & 127) * 8;       // staging col (shorts)
  const unsigned short* prebase = pre + (size_t)(bglob + l15) * 1024 + ibase + q * 4;

  #pragma unroll 1
  for (int t = 0; t < 512; ++t) {
    // prefetch pre early (plain cached load; latency hidden under poll)
    ushort4 pv = *(const ushort4*)(prebase + (size_t)t * 131072);

    const unsigned short* hprev = (t & 1) ? h1buf : h0buf;
    unsigned short* hnew        = (t & 1) ? h0buf : h1buf;

    if (t > 0) {
      const unsigned int tt = (unsigned int)t;
      for (;;) {
        unsigned int v;
        asm volatile("global_load_dword %0, %1, off sc1\n\ts_waitcnt vmcnt(0)"
                     : "=v"(v) : "v"(fpoll));
        if (__ballot(v < tt) == 0) break;   // all 64 producer-waves posted step t-1
      }
    }

    // stage h[16][1024] -> LDS via sc1 (MALL-coherent) loads
    {
      const unsigned short* hp = hprev + (size_t)(bglob + sb) * 1024 + sk;
      int4 r0, r1, r2, r3;
      asm volatile(
        "global_load_dwordx4 %0, %4, off sc1\n\t"
        "global_load_dwordx4 %1, %5, off sc1\n\t"
        "global_load_dwordx4 %2, %6, off sc1\n\t"
        "global_load_dwordx4 %3, %7, off sc1\n\t"
        "s_waitcnt vmcnt(0)"
        : "=&v"(r0), "=&v"(r1), "=&v"(r2), "=&v"(r3)
        : "v"(hp), "v"(hp + 4 * 1024), "v"(hp + 8 * 1024), "v"(hp + 12 * 1024));
      *(int4*)&hlds[sb][sk]      = r0;
      *(int4*)&hlds[sb + 4][sk]  = r1;
      *(int4*)&hlds[sb + 8][sk]  = r2;
      *(int4*)&hlds[sb + 12][sk] = r3;
    }
    __syncthreads();   // the only barrier per step

    f32x4 acc0 = {0.f, 0.f, 0.f, 0.f}, acc1 = {0.f, 0.f, 0.f, 0.f};
    #pragma unroll
    for (int kt = 0; kt < 32; kt += 2) {
      short8 b0 = *(const short8*)&hlds[l15][kt * 32 + q * 8];
      short8 b1 = *(const short8*)&hlds[l15][kt * 32 + 32 + q * 8];
      acc0 = __builtin_amdgcn_mfma_f32_16x16x32_bf16(A[kt],     b0, acc0, 0, 0, 0);
      acc1 = __builtin_amdgcn_mfma_f32_16x16x32_bf16(A[kt + 1], b1, acc1, 0, 0, 0);
    }

    // epilogue: D col=lane&15 -> batch, row=4q+r -> i
    float x0 = acc0[0] + acc1[0] + bf2f(pv.x) + bias.x;
    float x1 = acc0[1] + acc1[1] + bf2f(pv.y) + bias.y;
    float x2 = acc0[2] + acc1[2] + bf2f(pv.z) + bias.z;
    float x3 = acc0[3] + acc1[3] + bf2f(pv.w) + bias.w;
    uint2 pk;
    pk.x = pack2(fast_tanh(x0), fast_tanh(x1));
    pk.y = pack2(fast_tanh(x2), fast_tanh(x3));

    {
      unsigned short* dst = hnew + (size_t)(bglob + l15) * 1024 + ibase + q * 4;
      asm volatile("global_store_dwordx2 %0, %1, off sc1\n\ts_waitcnt vmcnt(0)"
                   : : "v"(dst), "v"(pk));
    }
    if (lane == 0) {
      unsigned int tv = (unsigned int)(t + 1);
      asm volatile("global_store_dword %0, %1, off sc1" : : "v"(fmine), "v"(tv));
    }
    __syncthreads();  // wg-wide: nobody reaches next poll until all waves posted
  }
}

// ---------------- final: sigmoid(h_T @ V^T + Vb) ----------------
__global__ __launch_bounds__(64) void final_out(const unsigned short* __restrict__ hT,
                                                const float* __restrict__ Vw,
                                                const float* __restrict__ Vb,
                                                float* __restrict__ out) {
  int b = blockIdx.x, lane = threadIdx.x;
  float sum = 0.f;
  #pragma unroll
  for (int k = 0; k < 16; ++k) {
    int i = k * 64 + lane;
    sum += bf2f(hT[b * 1024 + i]) * Vw[i];
  }
  #pragma unroll
  for (int off = 32; off; off >>= 1) sum += __shfl_down(sum, off);
  if (lane == 0) out[b] = 1.f / (1.f + expf(-(sum + Vb[0])));
}

extern "C" void kernel_launch(void* const* d_in, const int* in_sizes, int n_in,
                              void* d_out, int out_size, void* d_ws, size_t ws_size,
                              hipStream_t stream) {
  const int*   x   = (const int*)d_in[0];
  const float* emb = (const float*)d_in[1];
  const float* W_w = (const float*)d_in[2];
  const float* W_b = (const float*)d_in[3];
  const float* U_w = (const float*)d_in[4];
  const float* U_b = (const float*)d_in[5];
  const float* V_w = (const float*)d_in[6];
  const float* V_b = (const float*)d_in[7];
  float* out = (float*)d_out;
  char*  ws  = (char*)d_ws;

  unsigned short* Ubf = (unsigned short*)(ws + OFF_U);
  unsigned short* Wbf = (unsigned short*)(ws + OFF_W);
  unsigned short* pre = (unsigned short*)(ws + OFF_PRE);
  unsigned short* h0  = (unsigned short*)(ws + OFF_H0);
  unsigned short* h1  = (unsigned short*)(ws + OFF_H1);
  unsigned int*   cnt = (unsigned int*)(ws + OFF_CNT);

  // zero h0 (initial hidden state) + h1 + flags
  hipMemsetAsync(ws + OFF_H0, 0, (OFF_CNT - OFF_H0) + 0x1000, stream);

  cvt_bf16<<<1024, 256, 0, stream>>>(U_w, Ubf, 1024 * 1024 / 4);
  cvt_bf16<<<512, 256, 0, stream>>>(W_w, Wbf, 1024 * 512 / 4);

  pre_gemm<<<dim3(8, 512), 256, 0, stream>>>(x, emb, Wbf, pre);

  void* args[] = {&Ubf, &pre, &W_b, &U_b, &h0, &h1, &cnt};
  hipLaunchCooperativeKernel((void*)recurrence, dim3(64), dim3(512), args, 0, stream);

  final_out<<<128, 64, 0, stream>>>(h0, V_w, V_b, out);
}

// Round 5
// 1723.633 us; speedup vs baseline: 2.6817x; 1.0792x over previous
//
#include <hip/hip_runtime.h>
#include <hip/hip_bf16.h>

typedef short short8 __attribute__((ext_vector_type(8)));
typedef float f32x4 __attribute__((ext_vector_type(4)));

// ---- workspace layout (bytes) ----
#define OFF_U   0x0UL        // U bf16 [1024][1024]        2 MiB
#define OFF_W   0x200000UL   // W bf16 [1024][512]         1 MiB
#define OFF_PRE 0x300000UL   // pre bf16 [t=512][b=128][i=1024]  128 MiB
#define OFF_H0  0x8300000UL  // h buf0 bf16 [128][1024]    256 KiB
#define OFF_H1  0x8340000UL  // h buf1 bf16 [128][1024]    256 KiB
#define OFF_CNT 0x8380000UL  // flags uint[8 clusters][32] (one 128B line per cluster)

static __device__ __forceinline__ unsigned short f2bf(float f) {
  return __builtin_bit_cast(unsigned short, __float2bfloat16(f));
}
static __device__ __forceinline__ float bf2f(unsigned short u) {
  unsigned int v = (unsigned int)u << 16;
  return __builtin_bit_cast(float, v);
}
static __device__ __forceinline__ unsigned int pack2(float a, float b) {
  return (unsigned int)f2bf(a) | ((unsigned int)f2bf(b) << 16);
}
static __device__ __forceinline__ float fast_tanh(float x) {
  float xc = fminf(fmaxf(x, -10.f), 10.f);
  float e2 = __expf(2.f * xc);
  return 1.f - 2.f * __builtin_amdgcn_rcpf(e2 + 1.f);
}

// ---------------- fp32 -> bf16 bulk convert ----------------
__global__ __launch_bounds__(256) void cvt_bf16(const float* __restrict__ in,
                                                unsigned short* __restrict__ out, int n4) {
  int idx = blockIdx.x * 256 + threadIdx.x;
  if (idx < n4) {
    float4 v = *(const float4*)&in[idx * 4];
    uint2 p; p.x = pack2(v.x, v.y); p.y = pack2(v.z, v.w);
    *(uint2*)&out[idx * 4] = p;
  }
}

// ---------------- pre = gather(emb,x) @ W^T   (stored [t][b][i], bf16, NO bias) --------
__global__ __launch_bounds__(256) void pre_gemm(const int* __restrict__ x,
                                                const float* __restrict__ emb,
                                                const unsigned short* __restrict__ Wbf,
                                                unsigned short* __restrict__ pre) {
  const int t   = blockIdx.y;           // 0..511
  const int n0  = blockIdx.x * 128;     // i offset
  const int tid = threadIdx.x;
  const int lane = tid & 63, w = tid >> 6;
  const int q = lane >> 4, l15 = lane & 15;

  __shared__ unsigned short Alds[128][72];  // +8 pad
  __shared__ unsigned short Blds[128][72];
  __shared__ int tok[128];
  if (tid < 128) tok[tid] = x[tid * 512 + t];   // x[b][t]
  __syncthreads();

  f32x4 acc[4][4];
  #pragma unroll
  for (int a = 0; a < 4; ++a)
    #pragma unroll
    for (int b = 0; b < 4; ++b) acc[a][b] = {0.f, 0.f, 0.f, 0.f};

  const int wm = (w & 1) * 64, wn = (w >> 1) * 64;

  for (int k0 = 0; k0 < 512; k0 += 64) {
    #pragma unroll
    for (int it = 0; it < 8; ++it) {
      int idx = it * 256 + tid;
      int r = idx >> 4, c4 = (idx & 15) * 4;
      float4 v = *(const float4*)&emb[tok[r] * 512 + k0 + c4];
      uint2 p; p.x = pack2(v.x, v.y); p.y = pack2(v.z, v.w);
      *(uint2*)&Alds[r][c4] = p;
    }
    #pragma unroll
    for (int it = 0; it < 4; ++it) {
      int idx = it * 256 + tid;
      int r = idx >> 3, c8 = (idx & 7) * 8;
      *(int4*)&Blds[r][c8] = *(const int4*)&Wbf[(n0 + r) * 512 + k0 + c8];
    }
    __syncthreads();
    #pragma unroll
    for (int kt = 0; kt < 2; ++kt) {
      short8 af[4], bfr[4];
      #pragma unroll
      for (int mt = 0; mt < 4; ++mt) af[mt]  = *(const short8*)&Alds[wm + mt*16 + l15][kt*32 + q*8];
      #pragma unroll
      for (int nt = 0; nt < 4; ++nt) bfr[nt] = *(const short8*)&Blds[wn + nt*16 + l15][kt*32 + q*8];
      #pragma unroll
      for (int mt = 0; mt < 4; ++mt)
        #pragma unroll
        for (int nt = 0; nt < 4; ++nt)
          acc[mt][nt] = __builtin_amdgcn_mfma_f32_16x16x32_bf16(af[mt], bfr[nt], acc[mt][nt], 0, 0, 0);
    }
    __syncthreads();
  }
  #pragma unroll
  for (int mt = 0; mt < 4; ++mt) {
    int brow = wm + mt * 16 + q * 4;
    #pragma unroll
    for (int nt = 0; nt < 4; ++nt) {
      int i = n0 + wn + nt * 16 + l15;
      #pragma unroll
      for (int r = 0; r < 4; ++r)
        pre[(t * 128 + brow + r) * 1024 + i] = f2bf(acc[mt][nt][r]);
    }
  }
}

// ---------------- persistent recurrence ----------------
// 64 wgs = 8 clusters (16 batch) x 8 i-slices (128 rows). wg = 8 waves, each wave
// owns 16 i-rows x full K=1024; U fragments pinned resident (AGPR/VGPR file).
// Slim sc1 protocol (round-5): ONE flag per wg (8/cluster in one 128B line),
// ONE polling wave per wg. sc1 = MALL coherence point — the only cross-CU-coherent
// path on gfx950 (sc0 polls hit stale L1 and deadlock; agent-scope compiler atomics
// walk the whole L2 per access). In-loop asm carries NO "memory" clobber: volatile
// program order chains poll -> barrier -> stage -> barrier -> MFMA -> store -> flag,
// and U/pre/bias loads must stay hoistable/register-resident.
__global__ __launch_bounds__(512, 2) void recurrence(const unsigned short* __restrict__ Ubf,
                                                     const unsigned short* __restrict__ pre,
                                                     const float* __restrict__ Wb,
                                                     const float* __restrict__ Ub,
                                                     unsigned short* __restrict__ h0buf,
                                                     unsigned short* __restrict__ h1buf,
                                                     unsigned int* __restrict__ cnt) {
  const int c   = blockIdx.x & 7;        // cluster
  const int s   = blockIdx.x >> 3;       // i-slice
  const int tid = threadIdx.x;
  const int lane = tid & 63, wv = tid >> 6;
  const int q = lane >> 4, l15 = lane & 15;
  const int ibase = s * 128 + wv * 16;   // this wave's 16 i-rows
  const int bglob = c * 16;

  __shared__ unsigned short hlds[16][1032];   // [b][k], +8 pad (2-way max = free)

  // U A-fragments: 32 k-tiles, pinned resident (128 regs in the unified file)
  short8 A[32];
  {
    const unsigned short* Up = Ubf + (ibase + l15) * 1024 + q * 8;
    #pragma unroll
    for (int kt = 0; kt < 32; ++kt) A[kt] = *(const short8*)(Up + kt * 32);
  }
  #pragma unroll
  for (int kt = 0; kt < 32; ++kt) asm volatile("" : "+v"(A[kt]));  // opaque: forbid remat

  float4 bias;
  {
    int i0 = ibase + q * 4;
    float4 wb = *(const float4*)&Wb[i0];
    float4 ub = *(const float4*)&Ub[i0];
    bias = make_float4(wb.x + ub.x, wb.y + ub.y, wb.z + ub.z, wb.w + ub.w);
  }

  unsigned int* fbase = cnt + c * 32;             // this cluster's 128B flag line
  const unsigned int* fpoll = fbase + (lane & 7); // 8 flags, one sector
  unsigned int* fmine = fbase + s;
  const int sb = tid >> 7;              // staging row 0..3
  const int sk = (tid & 127) * 8;       // staging col (shorts)
  const unsigned short* prebase = pre + (size_t)(bglob + l15) * 1024 + ibase + q * 4;

  #pragma unroll 1
  for (int t = 0; t < 512; ++t) {
    // prefetch pre early (plain cached load; latency hidden under poll)
    ushort4 pv = *(const ushort4*)(prebase + (size_t)t * 131072);

    const unsigned short* hprev = (t & 1) ? h1buf : h0buf;
    unsigned short* hnew        = (t & 1) ? h0buf : h1buf;

    if (t > 0) {
      if (wv == 0) {
        const unsigned int tt = (unsigned int)t;
        for (;;) {
          unsigned int v;
          asm volatile("global_load_dword %0, %1, off sc1\n\ts_waitcnt vmcnt(0)"
                       : "=v"(v) : "v"(fpoll));
          if (__ballot(v < tt) == 0) break;   // all 8 producer-wgs posted step t-1
        }
      }
      __syncthreads();   // broadcast poll success to all waves
    }

    // stage h[16][1024] -> LDS via sc1 (MALL-coherent) loads
    {
      const unsigned short* hp = hprev + (size_t)(bglob + sb) * 1024 + sk;
      int4 r0, r1, r2, r3;
      asm volatile(
        "global_load_dwordx4 %0, %4, off sc1\n\t"
        "global_load_dwordx4 %1, %5, off sc1\n\t"
        "global_load_dwordx4 %2, %6, off sc1\n\t"
        "global_load_dwordx4 %3, %7, off sc1\n\t"
        "s_waitcnt vmcnt(0)"
        : "=&v"(r0), "=&v"(r1), "=&v"(r2), "=&v"(r3)
        : "v"(hp), "v"(hp + 4 * 1024), "v"(hp + 8 * 1024), "v"(hp + 12 * 1024));
      *(int4*)&hlds[sb][sk]      = r0;
      *(int4*)&hlds[sb + 4][sk]  = r1;
      *(int4*)&hlds[sb + 8][sk]  = r2;
      *(int4*)&hlds[sb + 12][sk] = r3;
    }
    __syncthreads();

    f32x4 acc0 = {0.f, 0.f, 0.f, 0.f}, acc1 = {0.f, 0.f, 0.f, 0.f};
    #pragma unroll
    for (int kt = 0; kt < 32; kt += 2) {
      short8 b0 = *(const short8*)&hlds[l15][kt * 32 + q * 8];
      short8 b1 = *(const short8*)&hlds[l15][kt * 32 + 32 + q * 8];
      acc0 = __builtin_amdgcn_mfma_f32_16x16x32_bf16(A[kt],     b0, acc0, 0, 0, 0);
      acc1 = __builtin_amdgcn_mfma_f32_16x16x32_bf16(A[kt + 1], b1, acc1, 0, 0, 0);
    }

    // epilogue: D col=lane&15 -> batch, row=4q+r -> i
    float x0 = acc0[0] + acc1[0] + bf2f(pv.x) + bias.x;
    float x1 = acc0[1] + acc1[1] + bf2f(pv.y) + bias.y;
    float x2 = acc0[2] + acc1[2] + bf2f(pv.z) + bias.z;
    float x3 = acc0[3] + acc1[3] + bf2f(pv.w) + bias.w;
    uint2 pk;
    pk.x = pack2(fast_tanh(x0), fast_tanh(x1));
    pk.y = pack2(fast_tanh(x2), fast_tanh(x3));

    {
      unsigned short* dst = hnew + (size_t)(bglob + l15) * 1024 + ibase + q * 4;
      asm volatile("global_store_dwordx2 %0, %1, off sc1\n\ts_waitcnt vmcnt(0)"
                   : : "v"(dst), "v"(pk));
    }
    __syncthreads();   // all waves' h stores are at the MALL
    if (tid == 0) {
      unsigned int tv = (unsigned int)(t + 1);
      asm volatile("global_store_dword %0, %1, off sc1\n\ts_waitcnt vmcnt(0)"
                   : : "v"(fmine), "v"(tv));
    }
    // wave 0's next-step poll re-reads own flag (acked above) -> no trailing barrier
  }
}

// ---------------- final: sigmoid(h_T @ V^T + Vb) ----------------
__global__ __launch_bounds__(64) void final_out(const unsigned short* __restrict__ hT,
                                                const float* __restrict__ Vw,
                                                const float* __restrict__ Vb,
                                                float* __restrict__ out) {
  int b = blockIdx.x, lane = threadIdx.x;
  float sum = 0.f;
  #pragma unroll
  for (int k = 0; k < 16; ++k) {
    int i = k * 64 + lane;
    sum += bf2f(hT[b * 1024 + i]) * Vw[i];
  }
  #pragma unroll
  for (int off = 32; off; off >>= 1) sum += __shfl_down(sum, off);
  if (lane == 0) out[b] = 1.f / (1.f + expf(-(sum + Vb[0])));
}

extern "C" void kernel_launch(void* const* d_in, const int* in_sizes, int n_in,
                              void* d_out, int out_size, void* d_ws, size_t ws_size,
                              hipStream_t stream) {
  const int*   x   = (const int*)d_in[0];
  const float* emb = (const float*)d_in[1];
  const float* W_w = (const float*)d_in[2];
  const float* W_b = (const float*)d_in[3];
  const float* U_w = (const float*)d_in[4];
  const float* U_b = (const float*)d_in[5];
  const float* V_w = (const float*)d_in[6];
  const float* V_b = (const float*)d_in[7];
  float* out = (float*)d_out;
  char*  ws  = (char*)d_ws;

  unsigned short* Ubf = (unsigned short*)(ws + OFF_U);
  unsigned short* Wbf = (unsigned short*)(ws + OFF_W);
  unsigned short* pre = (unsigned short*)(ws + OFF_PRE);
  unsigned short* h0  = (unsigned short*)(ws + OFF_H0);
  unsigned short* h1  = (unsigned short*)(ws + OFF_H1);
  unsigned int*   cnt = (unsigned int*)(ws + OFF_CNT);

  // zero h0 (initial hidden state) + h1 + flags
  hipMemsetAsync(ws + OFF_H0, 0, (OFF_CNT - OFF_H0) + 0x1000, stream);

  cvt_bf16<<<1024, 256, 0, stream>>>(U_w, Ubf, 1024 * 1024 / 4);
  cvt_bf16<<<512, 256, 0, stream>>>(W_w, Wbf, 1024 * 512 / 4);

  pre_gemm<<<dim3(8, 512), 256, 0, stream>>>(x, emb, Wbf, pre);

  void* args[] = {&Ubf, &pre, &W_b, &U_b, &h0, &h1, &cnt};
  hipLaunchCooperativeKernel((void*)recurrence, dim3(64), dim3(512), args, 0, stream);

  final_out<<<128, 64, 0, stream>>>(h0, V_w, V_b, out);
}

// Round 7
// 1720.242 us; speedup vs baseline: 2.6870x; 1.0020x over previous
//
#include <hip/hip_runtime.h>
#include <hip/hip_bf16.h>

typedef short short8 __attribute__((ext_vector_type(8)));
typedef float f32x4 __attribute__((ext_vector_type(4)));

// ---- workspace layout (bytes) ----
#define OFF_U   0x0UL        // U bf16 [1024][1024]        2 MiB
#define OFF_W   0x200000UL   // W bf16 [1024][512]         1 MiB
#define OFF_PRE 0x300000UL   // pre bf16 [t=512][b=128][i=1024]  128 MiB
#define OFF_H0  0x8300000UL  // h buf0 bf16 [128][1024]    256 KiB
#define OFF_H1  0x8340000UL  // h buf1 bf16 [128][1024]    256 KiB
#define OFF_CNT 0x8380000UL  // flags uint[8 clusters][32] (one 128B line per cluster)

static __device__ __forceinline__ unsigned short f2bf(float f) {
  return __builtin_bit_cast(unsigned short, __float2bfloat16(f));
}
static __device__ __forceinline__ float bf2f(unsigned short u) {
  unsigned int v = (unsigned int)u << 16;
  return __builtin_bit_cast(float, v);
}
static __device__ __forceinline__ unsigned int pack2(float a, float b) {
  return (unsigned int)f2bf(a) | ((unsigned int)f2bf(b) << 16);
}
static __device__ __forceinline__ float fast_tanh(float x) {
  float xc = fminf(fmaxf(x, -10.f), 10.f);
  float e2 = __expf(2.f * xc);
  return 1.f - 2.f * __builtin_amdgcn_rcpf(e2 + 1.f);
}

// ---------------- fp32 -> bf16 bulk convert ----------------
__global__ __launch_bounds__(256) void cvt_bf16(const float* __restrict__ in,
                                                unsigned short* __restrict__ out, int n4) {
  int idx = blockIdx.x * 256 + threadIdx.x;
  if (idx < n4) {
    float4 v = *(const float4*)&in[idx * 4];
    uint2 p; p.x = pack2(v.x, v.y); p.y = pack2(v.z, v.w);
    *(uint2*)&out[idx * 4] = p;
  }
}

// ---------------- pre = gather(emb,x) @ W^T   (stored [t][b][i], bf16, NO bias) --------
__global__ __launch_bounds__(256) void pre_gemm(const int* __restrict__ x,
                                                const float* __restrict__ emb,
                                                const unsigned short* __restrict__ Wbf,
                                                unsigned short* __restrict__ pre) {
  const int t   = blockIdx.y;           // 0..511
  const int n0  = blockIdx.x * 128;     // i offset
  const int tid = threadIdx.x;
  const int lane = tid & 63, w = tid >> 6;
  const int q = lane >> 4, l15 = lane & 15;

  __shared__ unsigned short Alds[128][72];  // +8 pad
  __shared__ unsigned short Blds[128][72];
  __shared__ int tok[128];
  if (tid < 128) tok[tid] = x[tid * 512 + t];   // x[b][t]
  __syncthreads();

  f32x4 acc[4][4];
  #pragma unroll
  for (int a = 0; a < 4; ++a)
    #pragma unroll
    for (int b = 0; b < 4; ++b) acc[a][b] = {0.f, 0.f, 0.f, 0.f};

  const int wm = (w & 1) * 64, wn = (w >> 1) * 64;

  for (int k0 = 0; k0 < 512; k0 += 64) {
    #pragma unroll
    for (int it = 0; it < 8; ++it) {
      int idx = it * 256 + tid;
      int r = idx >> 4, c4 = (idx & 15) * 4;
      float4 v = *(const float4*)&emb[tok[r] * 512 + k0 + c4];
      uint2 p; p.x = pack2(v.x, v.y); p.y = pack2(v.z, v.w);
      *(uint2*)&Alds[r][c4] = p;
    }
    #pragma unroll
    for (int it = 0; it < 4; ++it) {
      int idx = it * 256 + tid;
      int r = idx >> 3, c8 = (idx & 7) * 8;
      *(int4*)&Blds[r][c8] = *(const int4*)&Wbf[(n0 + r) * 512 + k0 + c8];
    }
    __syncthreads();
    #pragma unroll
    for (int kt = 0; kt < 2; ++kt) {
      short8 af[4], bfr[4];
      #pragma unroll
      for (int mt = 0; mt < 4; ++mt) af[mt]  = *(const short8*)&Alds[wm + mt*16 + l15][kt*32 + q*8];
      #pragma unroll
      for (int nt = 0; nt < 4; ++nt) bfr[nt] = *(const short8*)&Blds[wn + nt*16 + l15][kt*32 + q*8];
      #pragma unroll
      for (int mt = 0; mt < 4; ++mt)
        #pragma unroll
        for (int nt = 0; nt < 4; ++nt)
          acc[mt][nt] = __builtin_amdgcn_mfma_f32_16x16x32_bf16(af[mt], bfr[nt], acc[mt][nt], 0, 0, 0);
    }
    __syncthreads();
  }
  #pragma unroll
  for (int mt = 0; mt < 4; ++mt) {
    int brow = wm + mt * 16 + q * 4;
    #pragma unroll
    for (int nt = 0; nt < 4; ++nt) {
      int i = n0 + wn + nt * 16 + l15;
      #pragma unroll
      for (int r = 0; r < 4; ++r)
        pre[(t * 128 + brow + r) * 1024 + i] = f2bf(acc[mt][nt][r]);
    }
  }
}

// ---------------- persistent recurrence ----------------
// 64 wgs = 8 clusters (16 batch) x 8 i-slices (128 rows). wg = 8 waves, each wave
// owns 16 i-rows x full K=1024; U fragments pinned resident.
// Round-7 = round-6 protocol + UB fix:
//  * own 128-k slice short-circuits through LDS (epilogue writes hlds directly;
//    stage skips it; poll drops own flag).
//  * flag store has NO ack wait (dangling STORES are safe: HW latches source
//    regs at issue — compiler-generated code relies on this everywhere).
//  * poll runs 2 flag loads in flight (vmcnt(1) rotation), and — THE FIX —
//    drains vmcnt(0) on exit: a dangling LOAD's dest reg would otherwise be
//    reused by the allocator and clobbered at load completion (round-6 bug).
// All in-loop global accesses are volatile asm with NO "memory" clobber; the
// per-wave vmcnt FIFO + program order of volatile asm carries the dependence
// chain. pre/U/bias stay register/cache-resident.
__global__ __launch_bounds__(512, 2) void recurrence(const unsigned short* __restrict__ Ubf,
                                                     const unsigned short* __restrict__ pre,
                                                     const float* __restrict__ Wb,
                                                     const float* __restrict__ Ub,
                                                     unsigned short* __restrict__ h0buf,
                                                     unsigned short* __restrict__ h1buf,
                                                     unsigned int* __restrict__ cnt) {
  const int c   = blockIdx.x & 7;        // cluster
  const int s   = blockIdx.x >> 3;       // i-slice
  const int tid = threadIdx.x;
  const int lane = tid & 63, wv = tid >> 6;
  const int q = lane >> 4, l15 = lane & 15;
  const int ibase = s * 128 + wv * 16;   // this wave's 16 i-rows
  const int bglob = c * 16;

  __shared__ unsigned short hlds[16][1032];   // [b][k], +8 pad

  // zero own-slice region of hlds (h_{-1} = 0; stage never writes own slice)
  {
    int r = tid >> 5;                 // 0..15
    int kk = (tid & 31) * 4;          // 0..124
    *(uint2*)&hlds[r][s * 128 + kk] = make_uint2(0u, 0u);
  }

  // U A-fragments: 32 k-tiles, pinned resident (128 regs)
  short8 A[32];
  {
    const unsigned short* Up = Ubf + (ibase + l15) * 1024 + q * 8;
    #pragma unroll
    for (int kt = 0; kt < 32; ++kt) A[kt] = *(const short8*)(Up + kt * 32);
  }
  #pragma unroll
  for (int kt = 0; kt < 32; ++kt) asm volatile("" : "+v"(A[kt]));  // forbid remat

  float4 bias;
  {
    int i0 = ibase + q * 4;
    float4 wb = *(const float4*)&Wb[i0];
    float4 ub = *(const float4*)&Ub[i0];
    bias = make_float4(wb.x + ub.x, wb.y + ub.y, wb.z + ub.z, wb.w + ub.w);
  }

  unsigned int* fbase = cnt + c * 32;             // this cluster's 128B flag line
  const bool pact = (lane < 8) && (lane != s);    // poll participation (skip own)
  const unsigned int* fpoll = fbase + (lane & 7);
  unsigned int* fmine = fbase + s;
  const int sb = tid >> 7;              // staging row 0..3
  const int sk = (tid & 127) * 8;       // staging col (shorts)
  const bool notown = (sk >> 7) != s;   // this thread's 4 chunks are remote-slice
  const unsigned short* prebase = pre + (size_t)(bglob + l15) * 1024 + ibase + q * 4;

  __syncthreads();   // own-slice zero visible before t=0 MFMA

  #pragma unroll 1
  for (int t = 0; t < 512; ++t) {
    // pre prefetch — asm so our manual vmcnt FIFO stays the only counter model
    uint2 pvr;
    {
      const unsigned short* pp = prebase + (size_t)t * 131072;
      asm volatile("global_load_dwordx2 %0, %1, off" : "=v"(pvr) : "v"(pp));
    }

    const unsigned short* hprev = (t & 1) ? h1buf : h0buf;
    unsigned short* hnew        = (t & 1) ? h0buf : h1buf;

    if (t > 0) {
      if (wv == 0) {
        const unsigned int tt = (unsigned int)t;
        unsigned int va, vb;
        asm volatile("global_load_dword %0, %1, off sc1" : "=v"(va) : "v"(fpoll));
        for (;;) {
          asm volatile("global_load_dword %0, %1, off sc1\n\ts_waitcnt vmcnt(1)"
                       : "=v"(vb) : "v"(fpoll));
          unsigned int x = pact ? va : tt;
          if (__ballot(x < tt) == 0) break;     // va is complete (vmcnt(1) retired it)
          asm volatile("global_load_dword %0, %1, off sc1\n\ts_waitcnt vmcnt(1)"
                       : "=v"(va) : "v"(fpoll));
          x = pact ? vb : tt;
          if (__ballot(x < tt) == 0) break;
        }
        // UB FIX: drain the dangling poll load NOW, while va/vb are still live.
        // Leaving it in flight lets the allocator reuse its dest reg, which the
        // late completion then clobbers (round-6 replay failure).
        asm volatile("s_waitcnt vmcnt(0)");
      }
      __syncthreads();   // broadcast poll success
    }

    // stage remote slices of h[16][1024] -> LDS via sc1 loads; own slice skipped
    {
      const unsigned short* hp = hprev + (size_t)(bglob + sb) * 1024 + sk;
      int4 r0, r1, r2, r3;
      if (notown) {
        asm volatile(
          "global_load_dwordx4 %0, %4, off sc1\n\t"
          "global_load_dwordx4 %1, %5, off sc1\n\t"
          "global_load_dwordx4 %2, %6, off sc1\n\t"
          "global_load_dwordx4 %3, %7, off sc1"
          : "=&v"(r0), "=&v"(r1), "=&v"(r2), "=&v"(r3)
          : "v"(hp), "v"(hp + 4 * 1024), "v"(hp + 8 * 1024), "v"(hp + 12 * 1024));
      }
      asm volatile("s_waitcnt vmcnt(0)");   // drains stage + pv
      if (notown) {
        *(int4*)&hlds[sb][sk]      = r0;
        *(int4*)&hlds[sb + 4][sk]  = r1;
        *(int4*)&hlds[sb + 8][sk]  = r2;
        *(int4*)&hlds[sb + 12][sk] = r3;
      }
    }
    __syncthreads();

    f32x4 acc0 = {0.f, 0.f, 0.f, 0.f}, acc1 = {0.f, 0.f, 0.f, 0.f};
    #pragma unroll
    for (int kt = 0; kt < 32; kt += 2) {
      short8 b0 = *(const short8*)&hlds[l15][kt * 32 + q * 8];
      short8 b1 = *(const short8*)&hlds[l15][kt * 32 + 32 + q * 8];
      acc0 = __builtin_amdgcn_mfma_f32_16x16x32_bf16(A[kt],     b0, acc0, 0, 0, 0);
      acc1 = __builtin_amdgcn_mfma_f32_16x16x32_bf16(A[kt + 1], b1, acc1, 0, 0, 0);
    }
    __syncthreads();   // all waves done READING hlds before epilogue rewrites own slice

    // epilogue: D col=lane&15 -> batch, row=4q+r -> i
    float p0 = bf2f((unsigned short)(pvr.x & 0xffff));
    float p1 = bf2f((unsigned short)(pvr.x >> 16));
    float p2 = bf2f((unsigned short)(pvr.y & 0xffff));
    float p3 = bf2f((unsigned short)(pvr.y >> 16));
    float x0 = acc0[0] + acc1[0] + p0 + bias.x;
    float x1 = acc0[1] + acc1[1] + p1 + bias.y;
    float x2 = acc0[2] + acc1[2] + p2 + bias.z;
    float x3 = acc0[3] + acc1[3] + p3 + bias.w;
    uint2 pk;
    pk.x = pack2(fast_tanh(x0), fast_tanh(x1));
    pk.y = pack2(fast_tanh(x2), fast_tanh(x3));

    {
      const int i0 = ibase + q * 4;           // global i == own k index
      *(uint2*)&hlds[l15][i0] = pk;           // own-slice short-circuit (LDS)
      unsigned short* dst = hnew + (size_t)(bglob + l15) * 1024 + i0;
      asm volatile("global_store_dwordx2 %0, %1, off sc1\n\ts_waitcnt vmcnt(0)"
                   : : "v"(dst), "v"(pk));    // remote consumers' copy, drained
    }
    __syncthreads();   // all 8 waves' h stores are at the MALL
    if (tid == 0) {
      unsigned int tv = (unsigned int)(t + 1);
      asm volatile("global_store_dword %0, %1, off sc1" : : "v"(fmine), "v"(tv));
      // no ack wait: stores latch sources at issue; visibility ordering is
      // covered because all h stores were drained before the barrier above
    }
  }
}

// ---------------- final: sigmoid(h_T @ V^T + Vb) ----------------
__global__ __launch_bounds__(64) void final_out(const unsigned short* __restrict__ hT,
                                                const float* __restrict__ Vw,
                                                const float* __restrict__ Vb,
                                                float* __restrict__ out) {
  int b = blockIdx.x, lane = threadIdx.x;
  float sum = 0.f;
  #pragma unroll
  for (int k = 0; k < 16; ++k) {
    int i = k * 64 + lane;
    sum += bf2f(hT[b * 1024 + i]) * Vw[i];
  }
  #pragma unroll
  for (int off = 32; off; off >>= 1) sum += __shfl_down(sum, off);
  if (lane == 0) out[b] = 1.f / (1.f + expf(-(sum + Vb[0])));
}

extern "C" void kernel_launch(void* const* d_in, const int* in_sizes, int n_in,
                              void* d_out, int out_size, void* d_ws, size_t ws_size,
                              hipStream_t stream) {
  const int*   x   = (const int*)d_in[0];
  const float* emb = (const float*)d_in[1];
  const float* W_w = (const float*)d_in[2];
  const float* W_b = (const float*)d_in[3];
  const float* U_w = (const float*)d_in[4];
  const float* U_b = (const float*)d_in[5];
  const float* V_w = (const float*)d_in[6];
  const float* V_b = (const float*)d_in[7];
  float* out = (float*)d_out;
  char*  ws  = (char*)d_ws;

  unsigned short* Ubf = (unsigned short*)(ws + OFF_U);
  unsigned short* Wbf = (unsigned short*)(ws + OFF_W);
  unsigned short* pre = (unsigned short*)(ws + OFF_PRE);
  unsigned short* h0  = (unsigned short*)(ws + OFF_H0);
  unsigned short* h1  = (unsigned short*)(ws + OFF_H1);
  unsigned int*   cnt = (unsigned int*)(ws + OFF_CNT);

  // zero h0 (initial hidden state) + h1 + flags
  hipMemsetAsync(ws + OFF_H0, 0, (OFF_CNT - OFF_H0) + 0x1000, stream);

  cvt_bf16<<<1024, 256, 0, stream>>>(U_w, Ubf, 1024 * 1024 / 4);
  cvt_bf16<<<512, 256, 0, stream>>>(W_w, Wbf, 1024 * 512 / 4);

  pre_gemm<<<dim3(8, 512), 256, 0, stream>>>(x, emb, Wbf, pre);

  void* args[] = {&Ubf, &pre, &W_b, &U_b, &h0, &h1, &cnt};
  hipLaunchCooperativeKernel((void*)recurrence, dim3(64), dim3(512), args, 0, stream);

  final_out<<<128, 64, 0, stream>>>(h0, V_w, V_b, out);
}